// Round 18
// baseline (691.065 us; speedup 1.0000x reference)
//
#include <hip/hip_runtime.h>
#include <hip/hip_bf16.h>

typedef __bf16 bf16;
typedef __bf16 bf16x8 __attribute__((ext_vector_type(8)));
typedef __bf16 bf16x4 __attribute__((ext_vector_type(4)));
typedef float f32x4_t __attribute__((ext_vector_type(4)));

static constexpr int kDIM = 512;

// ---------------- ws layout (bytes) ----------------
static constexpr size_t OFF_QKVW = 0;                         // 1536*512 fp8
static constexpr size_t OFF_PROJW = 1572864;                  // 512*512 fp8
static constexpr size_t OFF_W1   = 2097152;                   // 2048*512 fp8
static constexpr size_t OFF_W2   = 4194304;                   // 512*2048 fp8 (K-permuted)
static constexpr size_t OFF_PTAB = 6291456;                   // 225*16 f32
static constexpr size_t OFF_A    = 8388608;                   // qkv mixed (134MB) / hidden fp8
static constexpr size_t OFF_B    = 276824064;                 // ln fp8 / attn-out fp8

typedef __attribute__((address_space(3))) uint32_t lds_u32_t;
typedef __attribute__((address_space(1))) const uint32_t glb_u32_t;
#define ASYNC_COPY16(gp, lp) __builtin_amdgcn_global_load_lds((glb_u32_t*)(gp), (lds_u32_t*)(lp), 16, 0, 0)
#define WAITV0() asm volatile("s_waitcnt vmcnt(0)" ::: "memory")

// ---------------- fp32 -> fp8 e4m3 cast with x64 scale ----------------
__global__ void cast_fp8_k(const float* __restrict__ in, unsigned char* __restrict__ out, int n4)
{
    int i = blockIdx.x * blockDim.x + threadIdx.x;
    if (i < n4) {
        float4 v = ((const float4*)in)[i];
        int p = __builtin_amdgcn_cvt_pk_fp8_f32(v.x * 64.0f, v.y * 64.0f, 0, false);
        p = __builtin_amdgcn_cvt_pk_fp8_f32(v.z * 64.0f, v.w * 64.0f, p, true);
        ((unsigned int*)out)[i] = (unsigned int)p;
    }
}

// ---------------- fp32 -> fp8 x64 cast with K-permutation pi (for w2) ----------------
// pi acts on the K index (col): j = [bx*128 | wc*64 | n*16 | c] -> [bx*128 | wc*64 | c*4 | n]
__global__ void cast_fp8_perm_k(const float* __restrict__ in, unsigned char* __restrict__ out,
                                int n4, int ncols)
{
    int i = blockIdx.x * blockDim.x + threadIdx.x;
    if (i < n4) {
        float4 v = ((const float4*)in)[i];
        int idx = i * 4;
        int row = idx / ncols;
        int j0 = idx - row * ncols;
        float vv[4] = {v.x, v.y, v.z, v.w};
#pragma unroll
        for (int t = 0; t < 4; ++t) {
            int j = j0 + t;
            int pj = (j & ~127) | (j & 64) | ((j & 15) << 2) | ((j >> 4) & 3);
            int p8 = __builtin_amdgcn_cvt_pk_fp8_f32(vv[t] * 64.0f, vv[t] * 64.0f, 0, false);
            out[(size_t)row * ncols + pj] = (unsigned char)(p8 & 0xff);
        }
    }
}

// ---------------- LayerNorm (+ optional LDA grouping) -> fp8 x32 ----------------
template<int GROUP>
__global__ __launch_bounds__(256)
void ln_k(const float* __restrict__ x, const float* __restrict__ gw,
          const float* __restrict__ bw, unsigned char* __restrict__ out)
{
    const int t = blockIdx.x * 4 + (threadIdx.x >> 6);
    const int lane = threadIdx.x & 63;
    const float* xp = x + (size_t)t * kDIM + lane * 8;
    float4 p0 = *(const float4*)xp;
    float4 p1 = *(const float4*)(xp + 4);
    float v[8] = {p0.x, p0.y, p0.z, p0.w, p1.x, p1.y, p1.z, p1.w};
    float s = 0.f;
#pragma unroll
    for (int i = 0; i < 8; ++i) s += v[i];
#pragma unroll
    for (int off = 32; off > 0; off >>= 1) s += __shfl_xor(s, off);
    const float mean = s * (1.0f / 512.0f);
    float q = 0.f;
#pragma unroll
    for (int i = 0; i < 8; ++i) { float d = v[i] - mean; q += d * d; }
#pragma unroll
    for (int off = 32; off > 0; off >>= 1) q += __shfl_xor(q, off);
    const float rstd = rsqrtf(q * (1.0f / 512.0f) + 1e-5f);
    size_t orow;
    if (GROUP) {
        int b = t >> 12, r = (t >> 6) & 63, c = t & 63;
        int g = b * 64 + (r & 7) * 8 + (c & 7);
        int n = (r >> 3) * 8 + (c >> 3);
        orow = (size_t)g * 64 + n;
    } else {
        orow = t;
    }
    float4 g0 = *(const float4*)(gw + lane * 8);
    float4 g1 = *(const float4*)(gw + lane * 8 + 4);
    float4 b0 = *(const float4*)(bw + lane * 8);
    float4 b1 = *(const float4*)(bw + lane * 8 + 4);
    float gg[8] = {g0.x, g0.y, g0.z, g0.w, g1.x, g1.y, g1.z, g1.w};
    float bb[8] = {b0.x, b0.y, b0.z, b0.w, b1.x, b1.y, b1.z, b1.w};
    float o[8];
#pragma unroll
    for (int i = 0; i < 8; ++i) o[i] = ((v[i] - mean) * rstd * gg[i] + bb[i]) * 32.0f;
    unsigned int lo = 0, hi = 0;
    lo = (unsigned int)__builtin_amdgcn_cvt_pk_fp8_f32(o[0], o[1], 0, false);
    lo = (unsigned int)__builtin_amdgcn_cvt_pk_fp8_f32(o[2], o[3], (int)lo, true);
    hi = (unsigned int)__builtin_amdgcn_cvt_pk_fp8_f32(o[4], o[5], 0, false);
    hi = (unsigned int)__builtin_amdgcn_cvt_pk_fp8_f32(o[6], o[7], (int)hi, true);
    uint2 u; u.x = lo; u.y = hi;
    *(uint2*)(out + orow * kDIM + lane * 8) = u;
}

// ---------------- dynamic position bias MLP: 225 rows, 2->32->32->32->16 ----------------
__device__ inline void ln32_relu(float* h, const float* g, const float* b)
{
    float m = 0.f;
#pragma unroll
    for (int i = 0; i < 32; ++i) m += h[i];
    m *= (1.0f / 32.0f);
    float v = 0.f;
#pragma unroll
    for (int i = 0; i < 32; ++i) { float d = h[i] - m; v += d * d; }
    v *= (1.0f / 32.0f);
    float r = rsqrtf(v + 1e-5f);
#pragma unroll
    for (int i = 0; i < 32; ++i) h[i] = fmaxf((h[i] - m) * r * g[i] + b[i], 0.f);
}

__global__ __launch_bounds__(256)
void posmlp_k(const float* __restrict__ w0, const float* __restrict__ b0,
              const float* __restrict__ g0, const float* __restrict__ bb0,
              const float* __restrict__ w1, const float* __restrict__ b1,
              const float* __restrict__ g1, const float* __restrict__ bb1,
              const float* __restrict__ w2, const float* __restrict__ b2,
              const float* __restrict__ g2, const float* __restrict__ bb2,
              const float* __restrict__ w3, const float* __restrict__ b3,
              float* __restrict__ ptab)
{
    int r = threadIdx.x;
    if (r >= 225) return;
    float in0 = (float)(r / 15) - 7.0f;
    float in1 = (float)(r % 15) - 7.0f;
    float h[32], h2[32];
#pragma unroll
    for (int o = 0; o < 32; ++o) h[o] = w0[o * 2] * in0 + w0[o * 2 + 1] * in1 + b0[o];
    ln32_relu(h, g0, bb0);
#pragma unroll
    for (int o = 0; o < 32; ++o) {
        float s = b1[o];
#pragma unroll
        for (int i = 0; i < 32; ++i) s += w1[o * 32 + i] * h[i];
        h2[o] = s;
    }
    ln32_relu(h2, g1, bb1);
#pragma unroll
    for (int o = 0; o < 32; ++o) {
        float s = b2[o];
#pragma unroll
        for (int i = 0; i < 32; ++i) s += w2[o * 32 + i] * h2[i];
        h[o] = s;
    }
    ln32_relu(h, g2, bb2);
#pragma unroll
    for (int o = 0; o < 16; ++o) {
        float s = b3[o];
#pragma unroll
        for (int i = 0; i < 32; ++i) s += w3[o * 32 + i] * h[i];
        ptab[r * 16 + o] = s;
    }
}

// ---------------- attention: fp8 Q/K (QK^T via fp8 MFMA), bf16 V/P/PV, fp8 O out ----------------
// qkv row layout (2048 B): [Q 512 fp8 x32 | K 512 fp8 x32 | V 1024 bf16]
__global__ __launch_bounds__(256)
void attn_mfma_k(const unsigned char* __restrict__ qkv, const float* __restrict__ ptab,
                 unsigned char* __restrict__ obuf)
{
    const int g  = blockIdx.x >> 1;
    const int hb = blockIdx.x & 1;
    const int w  = threadIdx.x >> 6;
    const int lane = threadIdx.x & 63;
    const int c = lane & 15, q = lane >> 4;

    __shared__ float ptl[16][240];                 // ptab transposed [head][idx]
    __shared__ alignas(16) bf16 pl[4][4096];       // per-wave P (64x64), XOR-swizzled
    __shared__ alignas(16) bf16 vt[4][2048];       // per-wave V^T (32 d x 64 m), swizzled

    for (int i = threadIdx.x; i < 3600; i += 256)
        ptl[i & 15][i >> 4] = ptab[i];
    __syncthreads();

    const size_t rowb = (size_t)g * 64;
    bf16* pw = pl[w];
    char* vw = (char*)vt[w];

    for (int hh = 0; hh < 2; ++hh) {
        const int head = hb * 8 + hh * 4 + w;
        const unsigned char* qb = qkv + rowb * 2048 + head * 32;

        // V rows bf16: coalesced 16B loads (issued first; land under QK^T)
        const bf16* vbase = (const bf16*)(qb + 1024 + head * 32);  // +head*64 B total
        bf16x8 vrow[4];
#pragma unroll
        for (int l = 0; l < 4; ++l)
            vrow[l] = *(const bf16x8*)((const bf16*)((const char*)vbase + (size_t)lane * 2048) + l * 8);

        // Q/K fp8 frags (8B/lane)
        long aq[4], bk[4];
#pragma unroll
        for (int i = 0; i < 4; ++i) {
            aq[i] = *(const long*)(qb + (size_t)(i * 16 + c) * 2048 + q * 8);
            bk[i] = *(const long*)(qb + 512 + (size_t)(i * 16 + c) * 2048 + q * 8);
        }

        // S = Q K^T (fp8, K=32 in one MFMA per tile pair)
        f32x4_t s[4][4];
#pragma unroll
        for (int i = 0; i < 4; ++i)
#pragma unroll
            for (int j = 0; j < 4; ++j)
                s[i][j] = __builtin_amdgcn_mfma_f32_16x16x32_fp8_fp8(aq[i], bk[j],
                          (f32x4_t){0.f, 0.f, 0.f, 0.f}, 0, 0, 0);

        // V^T -> LDS (row d, offset m*2 XOR (d&7)<<4)
#pragma unroll
        for (int l = 0; l < 4; ++l)
#pragma unroll
            for (int j = 0; j < 8; ++j) {
                const int d = l * 8 + j;
                *(bf16*)(vw + d * 128 + ((lane * 2) ^ ((d & 7) << 4))) = vrow[l][j];
            }

        // scale (incl. 1/(32*32) fp8 descale) + rel-pos bias + row softmax
        const float scale = 0.17677669529663687f / 1024.0f;
        float inv[4][4];
#pragma unroll
        for (int i = 0; i < 4; ++i)
#pragma unroll
            for (int jj = 0; jj < 4; ++jj) {
                const int n = i * 16 + q * 4 + jj;
                const int na = n >> 3, nu = n & 7;
                float mx = -1e30f;
#pragma unroll
                for (int j = 0; j < 4; ++j) {
                    const int m = j * 16 + c;
                    const int idx = (na - (m >> 3) + 7) * 15 + (nu - (m & 7) + 7);
                    float v = s[i][j][jj] * scale + ptl[head][idx];
                    s[i][j][jj] = v;
                    mx = fmaxf(mx, v);
                }
#pragma unroll
                for (int off = 1; off < 16; off <<= 1) mx = fmaxf(mx, __shfl_xor(mx, off));
                float sum = 0.f;
#pragma unroll
                for (int j = 0; j < 4; ++j) {
                    float e = __expf(s[i][j][jj] - mx);
                    s[i][j][jj] = e; sum += e;
                }
#pragma unroll
                for (int off = 1; off < 16; off <<= 1) sum += __shfl_xor(sum, off);
                inv[i][jj] = 1.0f / sum;
            }

        // P -> LDS (bf16, swizzled: byte ^= (row&7)<<4)
#pragma unroll
        for (int i = 0; i < 4; ++i)
#pragma unroll
            for (int jj = 0; jj < 4; ++jj) {
                const int n = i * 16 + q * 4 + jj;
                const int swz = (n & 7) << 4;
#pragma unroll
                for (int j = 0; j < 4; ++j) {
                    const int m = j * 16 + c;
                    *(bf16*)((char*)pw + n * 128 + ((m * 2) ^ swz)) = (bf16)s[i][j][jj];
                }
            }

        // V B-frags from LDS V^T
        bf16x8 bv[2][2];
#pragma unroll
        for (int ks = 0; ks < 2; ++ks)
#pragma unroll
            for (int dt = 0; dt < 2; ++dt)
                bv[ks][dt] = *(const bf16x8*)(vw + (dt * 16 + c) * 128 +
                              ((ks * 64 + q * 16) ^ ((c & 7) << 4)));

        // O = P V (bf16)
        f32x4_t o[4][2];
#pragma unroll
        for (int i = 0; i < 4; ++i)
#pragma unroll
            for (int dt = 0; dt < 2; ++dt)
                o[i][dt] = (f32x4_t){0.f, 0.f, 0.f, 0.f};
#pragma unroll
        for (int ks = 0; ks < 2; ++ks)
#pragma unroll
            for (int i = 0; i < 4; ++i) {
                const int n = i * 16 + c;
                bf16x8 ap = *(const bf16x8*)((char*)pw + n * 128 +
                             ((ks * 64 + q * 16) ^ ((n & 7) << 4)));
#pragma unroll
                for (int dt = 0; dt < 2; ++dt)
                    o[i][dt] = __builtin_amdgcn_mfma_f32_16x16x32_bf16(ap, bv[ks][dt], o[i][dt], 0, 0, 0);
            }

        // normalize + store fp8 x32
        unsigned char* ob = obuf + rowb * 512 + head * 32;
#pragma unroll
        for (int i = 0; i < 4; ++i)
#pragma unroll
            for (int dt = 0; dt < 2; ++dt)
#pragma unroll
                for (int jj = 0; jj < 4; ++jj) {
                    const int n = i * 16 + q * 4 + jj;
                    float val = o[i][dt][jj] * inv[i][jj] * 32.0f;
                    int p8 = __builtin_amdgcn_cvt_pk_fp8_f32(val, val, 0, false);
                    ob[(size_t)n * 512 + dt * 16 + c] = (unsigned char)(p8 & 0xff);
                }
    }
}

// ---------------- fp8 GEMM, COMPILE-TIME K ----------------
// vs R17: (a) 2 base pointers + compile-time chunk offsets (sg/ldsOff are l-independent)
//   -> VGPR back under the 64 step; (b) MODE 1 writes PERMUTED columns (pi: n*16+c -> c*4+n
//   within each 128-tile) so each lane packs its 4 n-values into ONE dword store
//   (stores 64->16, cvts 64->32). w2 is K-permuted to match (cast_fp8_perm_k) -> exact.
// BK=128, 32 KiB LDS, slot swizzle key=row&7, R7-proven vmcnt(0)+syncthreads pair.
// MODE 0: QKV mixed out | 1: gelu->fp8 permuted (MLP1) | 2: +resid ungroup f32 (proj) | 3: +resid f32 (MLP2)
template<int MODE, int NBX, int K>
__global__ __launch_bounds__(256, 2)
void gemm_fp8(const unsigned char* __restrict__ A, const unsigned char* __restrict__ Bw,
              const float* __restrict__ bias, const float* __restrict__ resid,
              void* __restrict__ outp, int N, float invs)
{
    __shared__ alignas(16) unsigned char As[128 * 128];  // 16 KiB
    __shared__ alignas(16) unsigned char Bs[128 * 128];  // 16 KiB
    const int tid = threadIdx.x;
    const int lane = tid & 63;
    const int w = tid >> 6;
    const int wr = w >> 1, wc = w & 1;
    const int c = lane & 15, q = lane >> 4;

    const int bid = blockIdx.y * NBX + blockIdx.x;
    const int nwg = gridDim.y * NBX;
    const int swz = (bid & 7) * (nwg >> 3) + (bid >> 3);
    const int by = swz / NBX;
    const int bx = swz - by * NBX;
    const int rowBase = by * 128;
    const int colBase = bx * 128;

    f32x4_t acc[4][4];
#pragma unroll
    for (int m = 0; m < 4; ++m)
#pragma unroll
        for (int n = 0; n < 4; ++n)
            acc[m][n] = (f32x4_t){0.f, 0.f, 0.f, 0.f};

    const int key = c & 7;               // row&7 for rows ...*16 + c
    const int hb8 = (q & 1) * 8;

    // staging bases: chunk l adds compile-time offsets l*32*K (global) / l*4096 (LDS)
    const int sg = (tid & 7) ^ ((tid >> 3) & 7);       // l-independent source slot
    const unsigned char* aBase = A + (size_t)(rowBase + (tid >> 3)) * K + sg * 16;
    const unsigned char* bBase = Bw + (size_t)(colBase + (tid >> 3)) * K + sg * 16;
    unsigned char* ldsA = As + (tid & 192) * 16;
    unsigned char* ldsB = Bs + (tid & 192) * 16;

    // loop-invariant LDS read byte offsets: kk-th MFMA step covers logical slots
    // {2kk, 2kk+1}; lane's logical slot = 2kk + (q>>1), physical = logical ^ key
    int sbo[4];
#pragma unroll
    for (int kk = 0; kk < 4; ++kk)
        sbo[kk] = (((2 * kk + (q >> 1)) ^ key) << 4) + hb8;

#pragma unroll
    for (int kt = 0; kt < K; kt += 128) {
#pragma unroll
        for (int l = 0; l < 4; ++l) {
            ASYNC_COPY16(aBase + (size_t)l * 32 * K + kt, ldsA + l * 4096);
            ASYNC_COPY16(bBase + (size_t)l * 32 * K + kt, ldsB + l * 4096);
        }
        WAITV0();
        __syncthreads();
#pragma unroll
        for (int kk = 0; kk < 4; ++kk) {
            const int sb = sbo[kk];
            long af[4], bfr[4];
#pragma unroll
            for (int m = 0; m < 4; ++m) {
                const int row = wr * 64 + m * 16 + c;
                af[m] = *(const long*)((const char*)As + row * 128 + sb);
            }
#pragma unroll
            for (int n = 0; n < 4; ++n) {
                const int row = wc * 64 + n * 16 + c;
                bfr[n] = *(const long*)((const char*)Bs + row * 128 + sb);
            }
#pragma unroll
            for (int m = 0; m < 4; ++m)
#pragma unroll
                for (int n = 0; n < 4; ++n)
                    acc[m][n] = __builtin_amdgcn_mfma_f32_16x16x32_fp8_fp8(af[m], bfr[n], acc[m][n], 0, 0, 0);
        }
        __syncthreads();
    }

#pragma unroll
    for (int m = 0; m < 4; ++m) {
#pragma unroll
        for (int jj = 0; jj < 4; ++jj) {
            int grow = rowBase + wr * 64 + m * 16 + q * 4 + jj;
            float vv[4];
#pragma unroll
            for (int n = 0; n < 4; ++n)
                vv[n] = acc[m][n][jj] * invs + bias[colBase + wc * 64 + n * 16 + c];
            if constexpr (MODE == 1) {
                // gelu each, pack 4 permuted-contiguous bytes, one dword store
#pragma unroll
                for (int n = 0; n < 4; ++n) {
                    float v = vv[n];
                    float e = __expf(1.5957691216057308f * (v + 0.044715f * v * v * v));
                    vv[n] = v * (e / (1.0f + e)) * 64.0f;
                }
                int p = __builtin_amdgcn_cvt_pk_fp8_f32(vv[0], vv[1], 0, false);
                p = __builtin_amdgcn_cvt_pk_fp8_f32(vv[2], vv[3], p, true);
                *(unsigned int*)((char*)outp + (size_t)grow * N + colBase + wc * 64 + c * 4) =
                    (unsigned int)p;
            } else {
#pragma unroll
                for (int n = 0; n < 4; ++n) {
                    int gcol = colBase + wc * 64 + n * 16 + c;
                    float v = vv[n];
                    if constexpr (MODE == 0) {
                        char* ob = (char*)outp;
                        if (gcol < 1024) {   // Q/K: fp8 x32 (tile-uniform branch)
                            int p8 = __builtin_amdgcn_cvt_pk_fp8_f32(v * 32.0f, v * 32.0f, 0, false);
                            ob[(size_t)grow * 2048 + gcol] = (char)(p8 & 0xff);
                        } else {             // V: bf16
                            *(bf16*)(ob + (size_t)grow * 2048 + 1024 + (size_t)(gcol - 1024) * 2) = (bf16)v;
                        }
                    } else if constexpr (MODE == 2) {
                        int g = grow >> 6, ns = grow & 63;
                        int b = g >> 6, i = (g >> 3) & 7, j = g & 7;
                        int a = ns >> 3, u = ns & 7;
                        int t = b * 4096 + (a * 8 + i) * 64 + (u * 8 + j);
                        size_t oi = (size_t)t * 512 + gcol;
                        ((float*)outp)[oi] = resid[oi] + v;
                    } else {
                        size_t oi = (size_t)grow * 512 + gcol;
                        ((float*)outp)[oi] = resid[oi] + v;
                    }
                }
            }
        }
    }
}

// ---------------- launcher ----------------
extern "C" void kernel_launch(void* const* d_in, const int* in_sizes, int n_in,
                              void* d_out, int out_size, void* d_ws, size_t ws_size,
                              hipStream_t stream)
{
    const float* x    = (const float*)d_in[0];
    const float* n1g  = (const float*)d_in[1];
    const float* n1b  = (const float*)d_in[2];
    const float* qkvw = (const float*)d_in[3];
    const float* qkvb = (const float*)d_in[4];
    const float* pjw  = (const float*)d_in[5];
    const float* pjb  = (const float*)d_in[6];
    const float* pw0  = (const float*)d_in[7];
    const float* pb0  = (const float*)d_in[8];
    const float* pg0  = (const float*)d_in[9];
    const float* pbb0 = (const float*)d_in[10];
    const float* pw1  = (const float*)d_in[11];
    const float* pb1  = (const float*)d_in[12];
    const float* pg1  = (const float*)d_in[13];
    const float* pbb1 = (const float*)d_in[14];
    const float* pw2  = (const float*)d_in[15];
    const float* pb2  = (const float*)d_in[16];
    const float* pg2  = (const float*)d_in[17];
    const float* pbb2 = (const float*)d_in[18];
    const float* pw3  = (const float*)d_in[19];
    const float* pb3  = (const float*)d_in[20];
    const float* n2g  = (const float*)d_in[21];
    const float* n2b  = (const float*)d_in[22];
    const float* w1   = (const float*)d_in[23];
    const float* b1   = (const float*)d_in[24];
    const float* w2   = (const float*)d_in[25];
    const float* b2   = (const float*)d_in[26];

    char* ws = (char*)d_ws;
    unsigned char* qkvw_f8 = (unsigned char*)(ws + OFF_QKVW);
    unsigned char* pjw_f8  = (unsigned char*)(ws + OFF_PROJW);
    unsigned char* w1_f8 = (unsigned char*)(ws + OFF_W1);
    unsigned char* w2_f8 = (unsigned char*)(ws + OFF_W2);
    float* ptab  = (float*)(ws + OFF_PTAB);
    unsigned char* bufA8 = (unsigned char*)(ws + OFF_A);   // qkv mixed / hidden fp8
    unsigned char* bufB8 = (unsigned char*)(ws + OFF_B);   // LN outs fp8 / attn-out fp8
    float* xout  = (float*)d_out;

    // weight casts (all fp8 x64; w2 K-permuted to match MLP1's permuted output)
    cast_fp8_k<<<(1536 * 512 / 4 + 255) / 256, 256, 0, stream>>>(qkvw, qkvw_f8, 1536 * 512 / 4);
    cast_fp8_k<<<(512 * 512 / 4 + 255) / 256, 256, 0, stream>>>(pjw, pjw_f8, 512 * 512 / 4);
    cast_fp8_k<<<(2048 * 512 / 4 + 255) / 256, 256, 0, stream>>>(w1, w1_f8, 2048 * 512 / 4);
    cast_fp8_perm_k<<<(512 * 2048 / 4 + 255) / 256, 256, 0, stream>>>(w2, w2_f8, 512 * 2048 / 4, 2048);

    // pos-bias table
    posmlp_k<<<1, 256, 0, stream>>>(pw0, pb0, pg0, pbb0, pw1, pb1, pg1, pbb1,
                                    pw2, pb2, pg2, pbb2, pw3, pb3, ptab);

    // LN1 + group -> bufB (fp8 x32)
    ln_k<1><<<16384, 256, 0, stream>>>(x, n1g, n1b, bufB8);

    // QKV (fp8) -> bufA mixed layout [Qf8|Kf8|Vbf16], row stride 2048 B; invs = 1/(32*64)
    gemm_fp8<0, 12, 512><<<dim3(12, 512), 256, 0, stream>>>(bufB8, qkvw_f8, qkvb, nullptr,
                                                            bufA8, 1536, 1.0f / 2048.0f);

    // attention -> bufB (fp8 x32)
    attn_mfma_k<<<2048, 256, 0, stream>>>(bufA8, ptab, bufB8);

    // proj (fp8) + ungroup + residual(x) -> d_out (x1); invs = 1/(32*64)
    gemm_fp8<2, 4, 512><<<dim3(4, 512), 256, 0, stream>>>(bufB8, pjw_f8, pjb, x,
                                                          xout, 512, 1.0f / 2048.0f);

    // LN2 -> bufB (fp8 x32)
    ln_k<0><<<16384, 256, 0, stream>>>(xout, n2g, n2b, bufB8);

    // MLP1 (fp8) + gelu -> bufA as fp8 x64, columns pi-permuted; invs = 1/(32*64)
    gemm_fp8<1, 16, 512><<<dim3(16, 512), 256, 0, stream>>>(bufB8, w1_f8, b1, nullptr,
                                                            bufA8, 2048, 1.0f / 2048.0f);

    // MLP2 (fp8, K-permuted both sides) + residual(x1) -> d_out; invs = 1/(64*64)
    gemm_fp8<3, 4, 2048><<<dim3(4, 512), 256, 0, stream>>>(bufA8, w2_f8, b2, xout,
                                                           xout, 512, 1.0f / 4096.0f);
}

// Round 19
// 657.098 us; speedup vs baseline: 1.0517x; 1.0517x over previous
//
#include <hip/hip_runtime.h>
#include <hip/hip_bf16.h>

typedef __bf16 bf16;
typedef __bf16 bf16x8 __attribute__((ext_vector_type(8)));
typedef __bf16 bf16x4 __attribute__((ext_vector_type(4)));
typedef float f32x4_t __attribute__((ext_vector_type(4)));

static constexpr int kDIM = 512;

// ---------------- ws layout (bytes) ----------------
static constexpr size_t OFF_QKVW = 0;                         // 1536*512 fp8
static constexpr size_t OFF_PROJW = 1572864;                  // 512*512 fp8
static constexpr size_t OFF_W1   = 2097152;                   // 2048*512 fp8
static constexpr size_t OFF_W2   = 4194304;                   // 512*2048 fp8 (K-permuted)
static constexpr size_t OFF_PTAB = 6291456;                   // 225*16 f32
static constexpr size_t OFF_A    = 8388608;                   // qkv mixed (134MB) / hidden fp8
static constexpr size_t OFF_B    = 276824064;                 // ln fp8 / attn-out fp8

typedef __attribute__((address_space(3))) uint32_t lds_u32_t;
typedef __attribute__((address_space(1))) const uint32_t glb_u32_t;
#define ASYNC_COPY16(gp, lp) __builtin_amdgcn_global_load_lds((glb_u32_t*)(gp), (lds_u32_t*)(lp), 16, 0, 0)
#define WAITV0() asm volatile("s_waitcnt vmcnt(0)" ::: "memory")

// ---------------- fp32 -> fp8 e4m3 cast with x64 scale ----------------
__global__ void cast_fp8_k(const float* __restrict__ in, unsigned char* __restrict__ out, int n4)
{
    int i = blockIdx.x * blockDim.x + threadIdx.x;
    if (i < n4) {
        float4 v = ((const float4*)in)[i];
        int p = __builtin_amdgcn_cvt_pk_fp8_f32(v.x * 64.0f, v.y * 64.0f, 0, false);
        p = __builtin_amdgcn_cvt_pk_fp8_f32(v.z * 64.0f, v.w * 64.0f, p, true);
        ((unsigned int*)out)[i] = (unsigned int)p;
    }
}

// ---------------- fp32 -> fp8 x64 cast with K-permutation pi (for w2) ----------------
// pi acts on the K index (col): j = [bx*128 | wc*64 | n*16 | c] -> [bx*128 | wc*64 | c*4 | n]
__global__ void cast_fp8_perm_k(const float* __restrict__ in, unsigned char* __restrict__ out,
                                int n4, int ncols)
{
    int i = blockIdx.x * blockDim.x + threadIdx.x;
    if (i < n4) {
        float4 v = ((const float4*)in)[i];
        int idx = i * 4;
        int row = idx / ncols;
        int j0 = idx - row * ncols;
        float vv[4] = {v.x, v.y, v.z, v.w};
#pragma unroll
        for (int t = 0; t < 4; ++t) {
            int j = j0 + t;
            int pj = (j & ~127) | (j & 64) | ((j & 15) << 2) | ((j >> 4) & 3);
            int p8 = __builtin_amdgcn_cvt_pk_fp8_f32(vv[t] * 64.0f, vv[t] * 64.0f, 0, false);
            out[(size_t)row * ncols + pj] = (unsigned char)(p8 & 0xff);
        }
    }
}

// ---------------- LayerNorm (+ optional LDA grouping) -> fp8 x32 ----------------
template<int GROUP>
__global__ __launch_bounds__(256)
void ln_k(const float* __restrict__ x, const float* __restrict__ gw,
          const float* __restrict__ bw, unsigned char* __restrict__ out)
{
    const int t = blockIdx.x * 4 + (threadIdx.x >> 6);
    const int lane = threadIdx.x & 63;
    const float* xp = x + (size_t)t * kDIM + lane * 8;
    float4 p0 = *(const float4*)xp;
    float4 p1 = *(const float4*)(xp + 4);
    float v[8] = {p0.x, p0.y, p0.z, p0.w, p1.x, p1.y, p1.z, p1.w};
    float s = 0.f;
#pragma unroll
    for (int i = 0; i < 8; ++i) s += v[i];
#pragma unroll
    for (int off = 32; off > 0; off >>= 1) s += __shfl_xor(s, off);
    const float mean = s * (1.0f / 512.0f);
    float q = 0.f;
#pragma unroll
    for (int i = 0; i < 8; ++i) { float d = v[i] - mean; q += d * d; }
#pragma unroll
    for (int off = 32; off > 0; off >>= 1) q += __shfl_xor(q, off);
    const float rstd = rsqrtf(q * (1.0f / 512.0f) + 1e-5f);
    size_t orow;
    if (GROUP) {
        int b = t >> 12, r = (t >> 6) & 63, c = t & 63;
        int g = b * 64 + (r & 7) * 8 + (c & 7);
        int n = (r >> 3) * 8 + (c >> 3);
        orow = (size_t)g * 64 + n;
    } else {
        orow = t;
    }
    float4 g0 = *(const float4*)(gw + lane * 8);
    float4 g1 = *(const float4*)(gw + lane * 8 + 4);
    float4 b0 = *(const float4*)(bw + lane * 8);
    float4 b1 = *(const float4*)(bw + lane * 8 + 4);
    float gg[8] = {g0.x, g0.y, g0.z, g0.w, g1.x, g1.y, g1.z, g1.w};
    float bb[8] = {b0.x, b0.y, b0.z, b0.w, b1.x, b1.y, b1.z, b1.w};
    float o[8];
#pragma unroll
    for (int i = 0; i < 8; ++i) o[i] = ((v[i] - mean) * rstd * gg[i] + bb[i]) * 32.0f;
    unsigned int lo = 0, hi = 0;
    lo = (unsigned int)__builtin_amdgcn_cvt_pk_fp8_f32(o[0], o[1], 0, false);
    lo = (unsigned int)__builtin_amdgcn_cvt_pk_fp8_f32(o[2], o[3], (int)lo, true);
    hi = (unsigned int)__builtin_amdgcn_cvt_pk_fp8_f32(o[4], o[5], 0, false);
    hi = (unsigned int)__builtin_amdgcn_cvt_pk_fp8_f32(o[6], o[7], (int)hi, true);
    uint2 u; u.x = lo; u.y = hi;
    *(uint2*)(out + orow * kDIM + lane * 8) = u;
}

// ---------------- dynamic position bias MLP: 225 rows, 2->32->32->32->16 ----------------
__device__ inline void ln32_relu(float* h, const float* g, const float* b)
{
    float m = 0.f;
#pragma unroll
    for (int i = 0; i < 32; ++i) m += h[i];
    m *= (1.0f / 32.0f);
    float v = 0.f;
#pragma unroll
    for (int i = 0; i < 32; ++i) { float d = h[i] - m; v += d * d; }
    v *= (1.0f / 32.0f);
    float r = rsqrtf(v + 1e-5f);
#pragma unroll
    for (int i = 0; i < 32; ++i) h[i] = fmaxf((h[i] - m) * r * g[i] + b[i], 0.f);
}

__global__ __launch_bounds__(256)
void posmlp_k(const float* __restrict__ w0, const float* __restrict__ b0,
              const float* __restrict__ g0, const float* __restrict__ bb0,
              const float* __restrict__ w1, const float* __restrict__ b1,
              const float* __restrict__ g1, const float* __restrict__ bb1,
              const float* __restrict__ w2, const float* __restrict__ b2,
              const float* __restrict__ g2, const float* __restrict__ bb2,
              const float* __restrict__ w3, const float* __restrict__ b3,
              float* __restrict__ ptab)
{
    int r = threadIdx.x;
    if (r >= 225) return;
    float in0 = (float)(r / 15) - 7.0f;
    float in1 = (float)(r % 15) - 7.0f;
    float h[32], h2[32];
#pragma unroll
    for (int o = 0; o < 32; ++o) h[o] = w0[o * 2] * in0 + w0[o * 2 + 1] * in1 + b0[o];
    ln32_relu(h, g0, bb0);
#pragma unroll
    for (int o = 0; o < 32; ++o) {
        float s = b1[o];
#pragma unroll
        for (int i = 0; i < 32; ++i) s += w1[o * 32 + i] * h[i];
        h2[o] = s;
    }
    ln32_relu(h2, g1, bb1);
#pragma unroll
    for (int o = 0; o < 32; ++o) {
        float s = b2[o];
#pragma unroll
        for (int i = 0; i < 32; ++i) s += w2[o * 32 + i] * h2[i];
        h[o] = s;
    }
    ln32_relu(h, g2, bb2);
#pragma unroll
    for (int o = 0; o < 16; ++o) {
        float s = b3[o];
#pragma unroll
        for (int i = 0; i < 32; ++i) s += w3[o * 32 + i] * h[i];
        ptab[r * 16 + o] = s;
    }
}

// ---------------- attention: fp8 Q/K (QK^T via fp8 MFMA), bf16 V/P/PV, fp8 O out ----------------
// qkv row layout (2048 B): [Q 512 fp8 x32 | K 512 fp8 x32 | V 1024 bf16]
// NOTE: Q and K columns are stored under a common within-head permutation pi2
// (by the QKV GEMM epilogue). The dot product over k is invariant under a common
// permutation of Q and K, so this kernel reads positional bytes unchanged.
__global__ __launch_bounds__(256)
void attn_mfma_k(const unsigned char* __restrict__ qkv, const float* __restrict__ ptab,
                 unsigned char* __restrict__ obuf)
{
    const int g  = blockIdx.x >> 1;
    const int hb = blockIdx.x & 1;
    const int w  = threadIdx.x >> 6;
    const int lane = threadIdx.x & 63;
    const int c = lane & 15, q = lane >> 4;

    __shared__ float ptl[16][240];                 // ptab transposed [head][idx]
    __shared__ alignas(16) bf16 pl[4][4096];       // per-wave P (64x64), XOR-swizzled
    __shared__ alignas(16) bf16 vt[4][2048];       // per-wave V^T (32 d x 64 m), swizzled

    for (int i = threadIdx.x; i < 3600; i += 256)
        ptl[i & 15][i >> 4] = ptab[i];
    __syncthreads();

    const size_t rowb = (size_t)g * 64;
    bf16* pw = pl[w];
    char* vw = (char*)vt[w];

    for (int hh = 0; hh < 2; ++hh) {
        const int head = hb * 8 + hh * 4 + w;
        const unsigned char* qb = qkv + rowb * 2048 + head * 32;

        // V rows bf16: coalesced 16B loads (issued first; land under QK^T)
        const bf16* vbase = (const bf16*)(qb + 1024 + head * 32);  // +head*64 B total
        bf16x8 vrow[4];
#pragma unroll
        for (int l = 0; l < 4; ++l)
            vrow[l] = *(const bf16x8*)((const bf16*)((const char*)vbase + (size_t)lane * 2048) + l * 8);

        // Q/K fp8 frags (8B/lane)
        long aq[4], bk[4];
#pragma unroll
        for (int i = 0; i < 4; ++i) {
            aq[i] = *(const long*)(qb + (size_t)(i * 16 + c) * 2048 + q * 8);
            bk[i] = *(const long*)(qb + 512 + (size_t)(i * 16 + c) * 2048 + q * 8);
        }

        // S = Q K^T (fp8, K=32 in one MFMA per tile pair)
        f32x4_t s[4][4];
#pragma unroll
        for (int i = 0; i < 4; ++i)
#pragma unroll
            for (int j = 0; j < 4; ++j)
                s[i][j] = __builtin_amdgcn_mfma_f32_16x16x32_fp8_fp8(aq[i], bk[j],
                          (f32x4_t){0.f, 0.f, 0.f, 0.f}, 0, 0, 0);

        // V^T -> LDS (row d, offset m*2 XOR (d&7)<<4)
#pragma unroll
        for (int l = 0; l < 4; ++l)
#pragma unroll
            for (int j = 0; j < 8; ++j) {
                const int d = l * 8 + j;
                *(bf16*)(vw + d * 128 + ((lane * 2) ^ ((d & 7) << 4))) = vrow[l][j];
            }

        // scale (incl. 1/(32*32) fp8 descale) + rel-pos bias + row softmax
        const float scale = 0.17677669529663687f / 1024.0f;
        float inv[4][4];
#pragma unroll
        for (int i = 0; i < 4; ++i)
#pragma unroll
            for (int jj = 0; jj < 4; ++jj) {
                const int n = i * 16 + q * 4 + jj;
                const int na = n >> 3, nu = n & 7;
                float mx = -1e30f;
#pragma unroll
                for (int j = 0; j < 4; ++j) {
                    const int m = j * 16 + c;
                    const int idx = (na - (m >> 3) + 7) * 15 + (nu - (m & 7) + 7);
                    float v = s[i][j][jj] * scale + ptl[head][idx];
                    s[i][j][jj] = v;
                    mx = fmaxf(mx, v);
                }
#pragma unroll
                for (int off = 1; off < 16; off <<= 1) mx = fmaxf(mx, __shfl_xor(mx, off));
                float sum = 0.f;
#pragma unroll
                for (int j = 0; j < 4; ++j) {
                    float e = __expf(s[i][j][jj] - mx);
                    s[i][j][jj] = e; sum += e;
                }
#pragma unroll
                for (int off = 1; off < 16; off <<= 1) sum += __shfl_xor(sum, off);
                inv[i][jj] = 1.0f / sum;
            }

        // P -> LDS (bf16, swizzled: byte ^= (row&7)<<4)
#pragma unroll
        for (int i = 0; i < 4; ++i)
#pragma unroll
            for (int jj = 0; jj < 4; ++jj) {
                const int n = i * 16 + q * 4 + jj;
                const int swz = (n & 7) << 4;
#pragma unroll
                for (int j = 0; j < 4; ++j) {
                    const int m = j * 16 + c;
                    *(bf16*)((char*)pw + n * 128 + ((m * 2) ^ swz)) = (bf16)s[i][j][jj];
                }
            }

        // V B-frags from LDS V^T
        bf16x8 bv[2][2];
#pragma unroll
        for (int ks = 0; ks < 2; ++ks)
#pragma unroll
            for (int dt = 0; dt < 2; ++dt)
                bv[ks][dt] = *(const bf16x8*)(vw + (dt * 16 + c) * 128 +
                              ((ks * 64 + q * 16) ^ ((c & 7) << 4)));

        // O = P V (bf16)
        f32x4_t o[4][2];
#pragma unroll
        for (int i = 0; i < 4; ++i)
#pragma unroll
            for (int dt = 0; dt < 2; ++dt)
                o[i][dt] = (f32x4_t){0.f, 0.f, 0.f, 0.f};
#pragma unroll
        for (int ks = 0; ks < 2; ++ks)
#pragma unroll
            for (int i = 0; i < 4; ++i) {
                const int n = i * 16 + c;
                bf16x8 ap = *(const bf16x8*)((char*)pw + n * 128 +
                             ((ks * 64 + q * 16) ^ ((n & 7) << 4)));
#pragma unroll
                for (int dt = 0; dt < 2; ++dt)
                    o[i][dt] = __builtin_amdgcn_mfma_f32_16x16x32_bf16(ap, bv[ks][dt], o[i][dt], 0, 0, 0);
            }

        // normalize + store fp8 x32
        unsigned char* ob = obuf + rowb * 512 + head * 32;
#pragma unroll
        for (int i = 0; i < 4; ++i)
#pragma unroll
            for (int dt = 0; dt < 2; ++dt)
#pragma unroll
                for (int jj = 0; jj < 4; ++jj) {
                    const int n = i * 16 + q * 4 + jj;
                    float val = o[i][dt][jj] * inv[i][jj] * 32.0f;
                    int p8 = __builtin_amdgcn_cvt_pk_fp8_f32(val, val, 0, false);
                    ob[(size_t)n * 512 + dt * 16 + c] = (unsigned char)(p8 & 0xff);
                }
    }
}

// ---------------- fp8 GEMM, COMPILE-TIME K ----------------
// vs R18: (a) kt loop unroll 2 (not full) + inline sb computation -> VGPR back under
//   the 64-wave-budget step (m69), occupancy ~40%; (b) MODE 0 Q/K columns stored
//   under within-head permutation pi2 ((n&1)*16+c -> c*2+(n&1)) applied to BOTH Q
//   and K -> dot product invariant, attention unchanged; lanes pack 2 bytes per
//   ushort store (Q/K stores halved).
// BK=128, 32 KiB LDS, slot swizzle key=row&7, R7-proven vmcnt(0)+syncthreads pair.
// MODE 0: QKV mixed out | 1: gelu->fp8 permuted (MLP1) | 2: +resid ungroup f32 (proj) | 3: +resid f32 (MLP2)
template<int MODE, int NBX, int K>
__global__ __launch_bounds__(256, 2)
void gemm_fp8(const unsigned char* __restrict__ A, const unsigned char* __restrict__ Bw,
              const float* __restrict__ bias, const float* __restrict__ resid,
              void* __restrict__ outp, int N, float invs)
{
    __shared__ alignas(16) unsigned char As[128 * 128];  // 16 KiB
    __shared__ alignas(16) unsigned char Bs[128 * 128];  // 16 KiB
    const int tid = threadIdx.x;
    const int lane = tid & 63;
    const int w = tid >> 6;
    const int wr = w >> 1, wc = w & 1;
    const int c = lane & 15, q = lane >> 4;

    const int bid = blockIdx.y * NBX + blockIdx.x;
    const int nwg = gridDim.y * NBX;
    const int swz = (bid & 7) * (nwg >> 3) + (bid >> 3);
    const int by = swz / NBX;
    const int bx = swz - by * NBX;
    const int rowBase = by * 128;
    const int colBase = bx * 128;

    f32x4_t acc[4][4];
#pragma unroll
    for (int m = 0; m < 4; ++m)
#pragma unroll
        for (int n = 0; n < 4; ++n)
            acc[m][n] = (f32x4_t){0.f, 0.f, 0.f, 0.f};

    const int key = c & 7;               // row&7 for rows ...*16 + c
    const int hb8 = (q & 1) * 8;

    // staging bases: chunk l adds compile-time offsets l*32*K (global) / l*4096 (LDS)
    const int sg = (tid & 7) ^ ((tid >> 3) & 7);       // l-independent source slot
    const unsigned char* aBase = A + (size_t)(rowBase + (tid >> 3)) * K + sg * 16;
    const unsigned char* bBase = Bw + (size_t)(colBase + (tid >> 3)) * K + sg * 16;
    unsigned char* ldsA = As + (tid & 192) * 16;
    unsigned char* ldsB = Bs + (tid & 192) * 16;

#pragma unroll 2
    for (int kt = 0; kt < K; kt += 128) {
#pragma unroll
        for (int l = 0; l < 4; ++l) {
            ASYNC_COPY16(aBase + (size_t)l * 32 * K + kt, ldsA + l * 4096);
            ASYNC_COPY16(bBase + (size_t)l * 32 * K + kt, ldsB + l * 4096);
        }
        WAITV0();
        __syncthreads();
#pragma unroll
        for (int kk = 0; kk < 4; ++kk) {
            // kk-th MFMA step covers logical 16B slots {2kk, 2kk+1};
            // lane's logical slot = 2kk + (q>>1), physical = logical ^ key
            const int sb = (((2 * kk + (q >> 1)) ^ key) << 4) + hb8;
            long af[4], bfr[4];
#pragma unroll
            for (int m = 0; m < 4; ++m) {
                const int row = wr * 64 + m * 16 + c;
                af[m] = *(const long*)((const char*)As + row * 128 + sb);
            }
#pragma unroll
            for (int n = 0; n < 4; ++n) {
                const int row = wc * 64 + n * 16 + c;
                bfr[n] = *(const long*)((const char*)Bs + row * 128 + sb);
            }
#pragma unroll
            for (int m = 0; m < 4; ++m)
#pragma unroll
                for (int n = 0; n < 4; ++n)
                    acc[m][n] = __builtin_amdgcn_mfma_f32_16x16x32_fp8_fp8(af[m], bfr[n], acc[m][n], 0, 0, 0);
        }
        __syncthreads();
    }

#pragma unroll
    for (int m = 0; m < 4; ++m) {
#pragma unroll
        for (int jj = 0; jj < 4; ++jj) {
            int grow = rowBase + wr * 64 + m * 16 + q * 4 + jj;
            float vv[4];
#pragma unroll
            for (int n = 0; n < 4; ++n)
                vv[n] = acc[m][n][jj] * invs + bias[colBase + wc * 64 + n * 16 + c];
            if constexpr (MODE == 0) {
                char* ob = (char*)outp;
                if (colBase < 1024) {
                    // Q/K: pi2 within-head pack: heads (wc*64+0) and (wc*64+32);
                    // pair (n=0,n=1) -> ushort at +c*2; pair (n=2,n=3) -> +32+c*2
                    int p0 = __builtin_amdgcn_cvt_pk_fp8_f32(vv[0] * 32.0f, vv[1] * 32.0f, 0, false);
                    int p1 = __builtin_amdgcn_cvt_pk_fp8_f32(vv[2] * 32.0f, vv[3] * 32.0f, 0, false);
                    *(unsigned short*)(ob + (size_t)grow * 2048 + colBase + wc * 64 + c * 2) =
                        (unsigned short)(p0 & 0xffff);
                    *(unsigned short*)(ob + (size_t)grow * 2048 + colBase + wc * 64 + 32 + c * 2) =
                        (unsigned short)(p1 & 0xffff);
                } else {
                    // V: bf16, original columns
#pragma unroll
                    for (int n = 0; n < 4; ++n) {
                        int gcol = colBase + wc * 64 + n * 16 + c;
                        *(bf16*)(ob + (size_t)grow * 2048 + 1024 + (size_t)(gcol - 1024) * 2) = (bf16)vv[n];
                    }
                }
            } else if constexpr (MODE == 1) {
                // gelu each, pack 4 permuted-contiguous bytes, one dword store
#pragma unroll
                for (int n = 0; n < 4; ++n) {
                    float v = vv[n];
                    float e = __expf(1.5957691216057308f * (v + 0.044715f * v * v * v));
                    vv[n] = v * (e / (1.0f + e)) * 64.0f;
                }
                int p = __builtin_amdgcn_cvt_pk_fp8_f32(vv[0], vv[1], 0, false);
                p = __builtin_amdgcn_cvt_pk_fp8_f32(vv[2], vv[3], p, true);
                *(unsigned int*)((char*)outp + (size_t)grow * N + colBase + wc * 64 + c * 4) =
                    (unsigned int)p;
            } else {
#pragma unroll
                for (int n = 0; n < 4; ++n) {
                    int gcol = colBase + wc * 64 + n * 16 + c;
                    float v = vv[n];
                    if constexpr (MODE == 2) {
                        int g = grow >> 6, ns = grow & 63;
                        int b = g >> 6, i = (g >> 3) & 7, j = g & 7;
                        int a = ns >> 3, u = ns & 7;
                        int t = b * 4096 + (a * 8 + i) * 64 + (u * 8 + j);
                        size_t oi = (size_t)t * 512 + gcol;
                        ((float*)outp)[oi] = resid[oi] + v;
                    } else {
                        size_t oi = (size_t)grow * 512 + gcol;
                        ((float*)outp)[oi] = resid[oi] + v;
                    }
                }
            }
        }
    }
}

// ---------------- launcher ----------------
extern "C" void kernel_launch(void* const* d_in, const int* in_sizes, int n_in,
                              void* d_out, int out_size, void* d_ws, size_t ws_size,
                              hipStream_t stream)
{
    const float* x    = (const float*)d_in[0];
    const float* n1g  = (const float*)d_in[1];
    const float* n1b  = (const float*)d_in[2];
    const float* qkvw = (const float*)d_in[3];
    const float* qkvb = (const float*)d_in[4];
    const float* pjw  = (const float*)d_in[5];
    const float* pjb  = (const float*)d_in[6];
    const float* pw0  = (const float*)d_in[7];
    const float* pb0  = (const float*)d_in[8];
    const float* pg0  = (const float*)d_in[9];
    const float* pbb0 = (const float*)d_in[10];
    const float* pw1  = (const float*)d_in[11];
    const float* pb1  = (const float*)d_in[12];
    const float* pg1  = (const float*)d_in[13];
    const float* pbb1 = (const float*)d_in[14];
    const float* pw2  = (const float*)d_in[15];
    const float* pb2  = (const float*)d_in[16];
    const float* pg2  = (const float*)d_in[17];
    const float* pbb2 = (const float*)d_in[18];
    const float* pw3  = (const float*)d_in[19];
    const float* pb3  = (const float*)d_in[20];
    const float* n2g  = (const float*)d_in[21];
    const float* n2b  = (const float*)d_in[22];
    const float* w1   = (const float*)d_in[23];
    const float* b1   = (const float*)d_in[24];
    const float* w2   = (const float*)d_in[25];
    const float* b2   = (const float*)d_in[26];

    char* ws = (char*)d_ws;
    unsigned char* qkvw_f8 = (unsigned char*)(ws + OFF_QKVW);
    unsigned char* pjw_f8  = (unsigned char*)(ws + OFF_PROJW);
    unsigned char* w1_f8 = (unsigned char*)(ws + OFF_W1);
    unsigned char* w2_f8 = (unsigned char*)(ws + OFF_W2);
    float* ptab  = (float*)(ws + OFF_PTAB);
    unsigned char* bufA8 = (unsigned char*)(ws + OFF_A);   // qkv mixed / hidden fp8
    unsigned char* bufB8 = (unsigned char*)(ws + OFF_B);   // LN outs fp8 / attn-out fp8
    float* xout  = (float*)d_out;

    // weight casts (all fp8 x64; w2 K-permuted to match MLP1's permuted output)
    cast_fp8_k<<<(1536 * 512 / 4 + 255) / 256, 256, 0, stream>>>(qkvw, qkvw_f8, 1536 * 512 / 4);
    cast_fp8_k<<<(512 * 512 / 4 + 255) / 256, 256, 0, stream>>>(pjw, pjw_f8, 512 * 512 / 4);
    cast_fp8_k<<<(2048 * 512 / 4 + 255) / 256, 256, 0, stream>>>(w1, w1_f8, 2048 * 512 / 4);
    cast_fp8_perm_k<<<(512 * 2048 / 4 + 255) / 256, 256, 0, stream>>>(w2, w2_f8, 512 * 2048 / 4, 2048);

    // pos-bias table
    posmlp_k<<<1, 256, 0, stream>>>(pw0, pb0, pg0, pbb0, pw1, pb1, pg1, pbb1,
                                    pw2, pb2, pg2, pbb2, pw3, pb3, ptab);

    // LN1 + group -> bufB (fp8 x32)
    ln_k<1><<<16384, 256, 0, stream>>>(x, n1g, n1b, bufB8);

    // QKV (fp8) -> bufA mixed layout [Qf8|Kf8|Vbf16] (Q/K pi2-permuted); invs = 1/(32*64)
    gemm_fp8<0, 12, 512><<<dim3(12, 512), 256, 0, stream>>>(bufB8, qkvw_f8, qkvb, nullptr,
                                                            bufA8, 1536, 1.0f / 2048.0f);

    // attention -> bufB (fp8 x32)
    attn_mfma_k<<<2048, 256, 0, stream>>>(bufA8, ptab, bufB8);

    // proj (fp8) + ungroup + residual(x) -> d_out (x1); invs = 1/(32*64)
    gemm_fp8<2, 4, 512><<<dim3(4, 512), 256, 0, stream>>>(bufB8, pjw_f8, pjb, x,
                                                          xout, 512, 1.0f / 2048.0f);

    // LN2 -> bufB (fp8 x32)
    ln_k<0><<<16384, 256, 0, stream>>>(xout, n2g, n2b, bufB8);

    // MLP1 (fp8) + gelu -> bufA as fp8 x64, columns pi-permuted; invs = 1/(32*64)
    gemm_fp8<1, 16, 512><<<dim3(16, 512), 256, 0, stream>>>(bufB8, w1_f8, b1, nullptr,
                                                            bufA8, 2048, 1.0f / 2048.0f);

    // MLP2 (fp8, K-permuted both sides) + residual(x1) -> d_out; invs = 1/(64*64)
    gemm_fp8<3, 4, 2048><<<dim3(4, 512), 256, 0, stream>>>(bufA8, w2_f8, b2, xout,
                                                           xout, 512, 1.0f / 4096.0f);
}

// Round 20
// 656.271 us; speedup vs baseline: 1.0530x; 1.0013x over previous
//
#include <hip/hip_runtime.h>
#include <hip/hip_bf16.h>

typedef __bf16 bf16;
typedef __bf16 bf16x8 __attribute__((ext_vector_type(8)));
typedef __bf16 bf16x4 __attribute__((ext_vector_type(4)));
typedef float f32x4_t __attribute__((ext_vector_type(4)));

static constexpr int kDIM = 512;

// ---------------- ws layout (bytes) ----------------
static constexpr size_t OFF_QKVW = 0;                         // 1536*512 fp8
static constexpr size_t OFF_PROJW = 1572864;                  // 512*512 fp8 (K-permuted pi2v)
static constexpr size_t OFF_W1   = 2097152;                   // 2048*512 fp8
static constexpr size_t OFF_W2   = 4194304;                   // 512*2048 fp8 (K-permuted)
static constexpr size_t OFF_PTAB = 6291456;                   // 225*16 f32
static constexpr size_t OFF_A    = 8388608;                   // qkv mixed (134MB) / hidden fp8
static constexpr size_t OFF_B    = 276824064;                 // ln fp8 / attn-out fp8

typedef __attribute__((address_space(3))) uint32_t lds_u32_t;
typedef __attribute__((address_space(1))) const uint32_t glb_u32_t;
#define ASYNC_COPY16(gp, lp) __builtin_amdgcn_global_load_lds((glb_u32_t*)(gp), (lds_u32_t*)(lp), 16, 0, 0)
#define WAITV0() asm volatile("s_waitcnt vmcnt(0)" ::: "memory")

// ---------------- fp32 -> fp8 e4m3 cast with x64 scale ----------------
__global__ void cast_fp8_k(const float* __restrict__ in, unsigned char* __restrict__ out, int n4)
{
    int i = blockIdx.x * blockDim.x + threadIdx.x;
    if (i < n4) {
        float4 v = ((const float4*)in)[i];
        int p = __builtin_amdgcn_cvt_pk_fp8_f32(v.x * 64.0f, v.y * 64.0f, 0, false);
        p = __builtin_amdgcn_cvt_pk_fp8_f32(v.z * 64.0f, v.w * 64.0f, p, true);
        ((unsigned int*)out)[i] = (unsigned int)p;
    }
}

// ---------------- fp32 -> fp8 x64 cast with K-permutation pi (for w2) ----------------
// pi acts on the K index (col): j -> [j&~127 | j&64 | (j&15)<<2 | (j>>4)&3]
__global__ void cast_fp8_perm_k(const float* __restrict__ in, unsigned char* __restrict__ out,
                                int n4, int ncols)
{
    int i = blockIdx.x * blockDim.x + threadIdx.x;
    if (i < n4) {
        float4 v = ((const float4*)in)[i];
        int idx = i * 4;
        int row = idx / ncols;
        int j0 = idx - row * ncols;
        float vv[4] = {v.x, v.y, v.z, v.w};
#pragma unroll
        for (int t = 0; t < 4; ++t) {
            int j = j0 + t;
            int pj = (j & ~127) | (j & 64) | ((j & 15) << 2) | ((j >> 4) & 3);
            int p8 = __builtin_amdgcn_cvt_pk_fp8_f32(vv[t] * 64.0f, vv[t] * 64.0f, 0, false);
            out[(size_t)row * ncols + pj] = (unsigned char)(p8 & 0xff);
        }
    }
}

// ---------------- fp32 -> fp8 x64 cast with pi2v K-permutation (for pjw) ----------------
// pi2v (within-head, head=32): j = H*32 + n16*16 + c -> H*32 + c*2 + n16
__global__ void cast_fp8_permv_k(const float* __restrict__ in, unsigned char* __restrict__ out,
                                 int n4, int ncols)
{
    int i = blockIdx.x * blockDim.x + threadIdx.x;
    if (i < n4) {
        float4 v = ((const float4*)in)[i];
        int idx = i * 4;
        int row = idx / ncols;
        int j0 = idx - row * ncols;
        float vv[4] = {v.x, v.y, v.z, v.w};
#pragma unroll
        for (int t = 0; t < 4; ++t) {
            int j = j0 + t;
            int pj = (j & ~31) | ((j & 15) << 1) | ((j >> 4) & 1);
            int p8 = __builtin_amdgcn_cvt_pk_fp8_f32(vv[t] * 64.0f, vv[t] * 64.0f, 0, false);
            out[(size_t)row * ncols + pj] = (unsigned char)(p8 & 0xff);
        }
    }
}

// ---------------- LayerNorm (+ optional LDA grouping) -> fp8 x32 ----------------
template<int GROUP>
__global__ __launch_bounds__(256)
void ln_k(const float* __restrict__ x, const float* __restrict__ gw,
          const float* __restrict__ bw, unsigned char* __restrict__ out)
{
    const int t = blockIdx.x * 4 + (threadIdx.x >> 6);
    const int lane = threadIdx.x & 63;
    const float* xp = x + (size_t)t * kDIM + lane * 8;
    float4 p0 = *(const float4*)xp;
    float4 p1 = *(const float4*)(xp + 4);
    float v[8] = {p0.x, p0.y, p0.z, p0.w, p1.x, p1.y, p1.z, p1.w};
    float s = 0.f;
#pragma unroll
    for (int i = 0; i < 8; ++i) s += v[i];
#pragma unroll
    for (int off = 32; off > 0; off >>= 1) s += __shfl_xor(s, off);
    const float mean = s * (1.0f / 512.0f);
    float q = 0.f;
#pragma unroll
    for (int i = 0; i < 8; ++i) { float d = v[i] - mean; q += d * d; }
#pragma unroll
    for (int off = 32; off > 0; off >>= 1) q += __shfl_xor(q, off);
    const float rstd = rsqrtf(q * (1.0f / 512.0f) + 1e-5f);
    size_t orow;
    if (GROUP) {
        int b = t >> 12, r = (t >> 6) & 63, c = t & 63;
        int g = b * 64 + (r & 7) * 8 + (c & 7);
        int n = (r >> 3) * 8 + (c >> 3);
        orow = (size_t)g * 64 + n;
    } else {
        orow = t;
    }
    float4 g0 = *(const float4*)(gw + lane * 8);
    float4 g1 = *(const float4*)(gw + lane * 8 + 4);
    float4 b0 = *(const float4*)(bw + lane * 8);
    float4 b1 = *(const float4*)(bw + lane * 8 + 4);
    float gg[8] = {g0.x, g0.y, g0.z, g0.w, g1.x, g1.y, g1.z, g1.w};
    float bb[8] = {b0.x, b0.y, b0.z, b0.w, b1.x, b1.y, b1.z, b1.w};
    float o[8];
#pragma unroll
    for (int i = 0; i < 8; ++i) o[i] = ((v[i] - mean) * rstd * gg[i] + bb[i]) * 32.0f;
    unsigned int lo = 0, hi = 0;
    lo = (unsigned int)__builtin_amdgcn_cvt_pk_fp8_f32(o[0], o[1], 0, false);
    lo = (unsigned int)__builtin_amdgcn_cvt_pk_fp8_f32(o[2], o[3], (int)lo, true);
    hi = (unsigned int)__builtin_amdgcn_cvt_pk_fp8_f32(o[4], o[5], 0, false);
    hi = (unsigned int)__builtin_amdgcn_cvt_pk_fp8_f32(o[6], o[7], (int)hi, true);
    uint2 u; u.x = lo; u.y = hi;
    *(uint2*)(out + orow * kDIM + lane * 8) = u;
}

// ---------------- dynamic position bias MLP: 225 rows, 2->32->32->32->16 ----------------
__device__ inline void ln32_relu(float* h, const float* g, const float* b)
{
    float m = 0.f;
#pragma unroll
    for (int i = 0; i < 32; ++i) m += h[i];
    m *= (1.0f / 32.0f);
    float v = 0.f;
#pragma unroll
    for (int i = 0; i < 32; ++i) { float d = h[i] - m; v += d * d; }
    v *= (1.0f / 32.0f);
    float r = rsqrtf(v + 1e-5f);
#pragma unroll
    for (int i = 0; i < 32; ++i) h[i] = fmaxf((h[i] - m) * r * g[i] + b[i], 0.f);
}

__global__ __launch_bounds__(256)
void posmlp_k(const float* __restrict__ w0, const float* __restrict__ b0,
              const float* __restrict__ g0, const float* __restrict__ bb0,
              const float* __restrict__ w1, const float* __restrict__ b1,
              const float* __restrict__ g1, const float* __restrict__ bb1,
              const float* __restrict__ w2, const float* __restrict__ b2,
              const float* __restrict__ g2, const float* __restrict__ bb2,
              const float* __restrict__ w3, const float* __restrict__ b3,
              float* __restrict__ ptab)
{
    int r = threadIdx.x;
    if (r >= 225) return;
    float in0 = (float)(r / 15) - 7.0f;
    float in1 = (float)(r % 15) - 7.0f;
    float h[32], h2[32];
#pragma unroll
    for (int o = 0; o < 32; ++o) h[o] = w0[o * 2] * in0 + w0[o * 2 + 1] * in1 + b0[o];
    ln32_relu(h, g0, bb0);
#pragma unroll
    for (int o = 0; o < 32; ++o) {
        float s = b1[o];
#pragma unroll
        for (int i = 0; i < 32; ++i) s += w1[o * 32 + i] * h[i];
        h2[o] = s;
    }
    ln32_relu(h2, g1, bb1);
#pragma unroll
    for (int o = 0; o < 32; ++o) {
        float s = b2[o];
#pragma unroll
        for (int i = 0; i < 32; ++i) s += w2[o * 32 + i] * h2[i];
        h[o] = s;
    }
    ln32_relu(h, g2, bb2);
#pragma unroll
    for (int o = 0; o < 16; ++o) {
        float s = b3[o];
#pragma unroll
        for (int i = 0; i < 32; ++i) s += w3[o * 32 + i] * h[i];
        ptab[r * 16 + o] = s;
    }
}

// ---------------- attention: fp8 Q/K (QK^T via fp8 MFMA), bf16 V/P/PV, fp8 O out ----------------
// qkv row layout (2048 B): [Q 512 fp8 x32 | K 512 fp8 x32 | V 1024 bf16]
// Q/K and V columns are stored under common within-head permutations (applied by the
// QKV epilogue). QK^T is invariant (common perm of Q,K); V's perm propagates to O's
// columns, compensated by the pi2v-permuted proj weight. This kernel reads positionally.
__global__ __launch_bounds__(256)
void attn_mfma_k(const unsigned char* __restrict__ qkv, const float* __restrict__ ptab,
                 unsigned char* __restrict__ obuf)
{
    const int g  = blockIdx.x >> 1;
    const int hb = blockIdx.x & 1;
    const int w  = threadIdx.x >> 6;
    const int lane = threadIdx.x & 63;
    const int c = lane & 15, q = lane >> 4;

    __shared__ float ptl[16][240];                 // ptab transposed [head][idx]
    __shared__ alignas(16) bf16 pl[4][4096];       // per-wave P (64x64), XOR-swizzled
    __shared__ alignas(16) bf16 vt[4][2048];       // per-wave V^T (32 d x 64 m), swizzled

    for (int i = threadIdx.x; i < 3600; i += 256)
        ptl[i & 15][i >> 4] = ptab[i];
    __syncthreads();

    const size_t rowb = (size_t)g * 64;
    bf16* pw = pl[w];
    char* vw = (char*)vt[w];

    for (int hh = 0; hh < 2; ++hh) {
        const int head = hb * 8 + hh * 4 + w;
        const unsigned char* qb = qkv + rowb * 2048 + head * 32;

        // V rows bf16: coalesced 16B loads (issued first; land under QK^T)
        const bf16* vbase = (const bf16*)(qb + 1024 + head * 32);  // +head*64 B total
        bf16x8 vrow[4];
#pragma unroll
        for (int l = 0; l < 4; ++l)
            vrow[l] = *(const bf16x8*)((const bf16*)((const char*)vbase + (size_t)lane * 2048) + l * 8);

        // Q/K fp8 frags (8B/lane)
        long aq[4], bk[4];
#pragma unroll
        for (int i = 0; i < 4; ++i) {
            aq[i] = *(const long*)(qb + (size_t)(i * 16 + c) * 2048 + q * 8);
            bk[i] = *(const long*)(qb + 512 + (size_t)(i * 16 + c) * 2048 + q * 8);
        }

        // S = Q K^T (fp8, K=32 in one MFMA per tile pair)
        f32x4_t s[4][4];
#pragma unroll
        for (int i = 0; i < 4; ++i)
#pragma unroll
            for (int j = 0; j < 4; ++j)
                s[i][j] = __builtin_amdgcn_mfma_f32_16x16x32_fp8_fp8(aq[i], bk[j],
                          (f32x4_t){0.f, 0.f, 0.f, 0.f}, 0, 0, 0);

        // V^T -> LDS (row d, offset m*2 XOR (d&7)<<4)
#pragma unroll
        for (int l = 0; l < 4; ++l)
#pragma unroll
            for (int j = 0; j < 8; ++j) {
                const int d = l * 8 + j;
                *(bf16*)(vw + d * 128 + ((lane * 2) ^ ((d & 7) << 4))) = vrow[l][j];
            }

        // scale (incl. 1/(32*32) fp8 descale) + rel-pos bias + row softmax
        const float scale = 0.17677669529663687f / 1024.0f;
        float inv[4][4];
#pragma unroll
        for (int i = 0; i < 4; ++i)
#pragma unroll
            for (int jj = 0; jj < 4; ++jj) {
                const int n = i * 16 + q * 4 + jj;
                const int na = n >> 3, nu = n & 7;
                float mx = -1e30f;
#pragma unroll
                for (int j = 0; j < 4; ++j) {
                    const int m = j * 16 + c;
                    const int idx = (na - (m >> 3) + 7) * 15 + (nu - (m & 7) + 7);
                    float v = s[i][j][jj] * scale + ptl[head][idx];
                    s[i][j][jj] = v;
                    mx = fmaxf(mx, v);
                }
#pragma unroll
                for (int off = 1; off < 16; off <<= 1) mx = fmaxf(mx, __shfl_xor(mx, off));
                float sum = 0.f;
#pragma unroll
                for (int j = 0; j < 4; ++j) {
                    float e = __expf(s[i][j][jj] - mx);
                    s[i][j][jj] = e; sum += e;
                }
#pragma unroll
                for (int off = 1; off < 16; off <<= 1) sum += __shfl_xor(sum, off);
                inv[i][jj] = __fdividef(1.0f, sum);
            }

        // P -> LDS (bf16, swizzled: byte ^= (row&7)<<4)
#pragma unroll
        for (int i = 0; i < 4; ++i)
#pragma unroll
            for (int jj = 0; jj < 4; ++jj) {
                const int n = i * 16 + q * 4 + jj;
                const int swz = (n & 7) << 4;
#pragma unroll
                for (int j = 0; j < 4; ++j) {
                    const int m = j * 16 + c;
                    *(bf16*)((char*)pw + n * 128 + ((m * 2) ^ swz)) = (bf16)s[i][j][jj];
                }
            }

        // V B-frags from LDS V^T
        bf16x8 bv[2][2];
#pragma unroll
        for (int ks = 0; ks < 2; ++ks)
#pragma unroll
            for (int dt = 0; dt < 2; ++dt)
                bv[ks][dt] = *(const bf16x8*)(vw + (dt * 16 + c) * 128 +
                              ((ks * 64 + q * 16) ^ ((c & 7) << 4)));

        // O = P V (bf16)
        f32x4_t o[4][2];
#pragma unroll
        for (int i = 0; i < 4; ++i)
#pragma unroll
            for (int dt = 0; dt < 2; ++dt)
                o[i][dt] = (f32x4_t){0.f, 0.f, 0.f, 0.f};
#pragma unroll
        for (int ks = 0; ks < 2; ++ks)
#pragma unroll
            for (int i = 0; i < 4; ++i) {
                const int n = i * 16 + c;
                bf16x8 ap = *(const bf16x8*)((char*)pw + n * 128 +
                             ((ks * 64 + q * 16) ^ ((n & 7) << 4)));
#pragma unroll
                for (int dt = 0; dt < 2; ++dt)
                    o[i][dt] = __builtin_amdgcn_mfma_f32_16x16x32_bf16(ap, bv[ks][dt], o[i][dt], 0, 0, 0);
            }

        // normalize + store fp8 x32
        unsigned char* ob = obuf + rowb * 512 + head * 32;
#pragma unroll
        for (int i = 0; i < 4; ++i)
#pragma unroll
            for (int dt = 0; dt < 2; ++dt)
#pragma unroll
                for (int jj = 0; jj < 4; ++jj) {
                    const int n = i * 16 + q * 4 + jj;
                    float val = o[i][dt][jj] * inv[i][jj] * 32.0f;
                    int p8 = __builtin_amdgcn_cvt_pk_fp8_f32(val, val, 0, false);
                    ob[(size_t)n * 512 + dt * 16 + c] = (unsigned char)(p8 & 0xff);
                }
    }
}

// ---------------- fp8 GEMM, COMPILE-TIME K ----------------
// vs R19: (a) MODE 1 gelu uses __fdividef (v_rcp) instead of precise div (~8 VALU x64
//   saved per thread; the epilogue was ~60% of MLP1's VALU); (b) MODE 0 V columns
//   stored under pi2v within-head perm -> 2 dword stores instead of 4 bf16 stores;
//   pjw's K-dim is permuted to match (cast_fp8_permv_k) -> exact.
// BK=128, 32 KiB LDS, slot swizzle key=row&7, R7-proven vmcnt(0)+syncthreads pair.
// MODE 0: QKV mixed out | 1: gelu->fp8 permuted (MLP1) | 2: +resid ungroup f32 (proj) | 3: +resid f32 (MLP2)
template<int MODE, int NBX, int K>
__global__ __launch_bounds__(256, 2)
void gemm_fp8(const unsigned char* __restrict__ A, const unsigned char* __restrict__ Bw,
              const float* __restrict__ bias, const float* __restrict__ resid,
              void* __restrict__ outp, int N, float invs)
{
    __shared__ alignas(16) unsigned char As[128 * 128];  // 16 KiB
    __shared__ alignas(16) unsigned char Bs[128 * 128];  // 16 KiB
    const int tid = threadIdx.x;
    const int lane = tid & 63;
    const int w = tid >> 6;
    const int wr = w >> 1, wc = w & 1;
    const int c = lane & 15, q = lane >> 4;

    const int bid = blockIdx.y * NBX + blockIdx.x;
    const int nwg = gridDim.y * NBX;
    const int swz = (bid & 7) * (nwg >> 3) + (bid >> 3);
    const int by = swz / NBX;
    const int bx = swz - by * NBX;
    const int rowBase = by * 128;
    const int colBase = bx * 128;

    f32x4_t acc[4][4];
#pragma unroll
    for (int m = 0; m < 4; ++m)
#pragma unroll
        for (int n = 0; n < 4; ++n)
            acc[m][n] = (f32x4_t){0.f, 0.f, 0.f, 0.f};

    const int key = c & 7;               // row&7 for rows ...*16 + c
    const int hb8 = (q & 1) * 8;

    // staging bases: chunk l adds compile-time offsets l*32*K (global) / l*4096 (LDS)
    const int sg = (tid & 7) ^ ((tid >> 3) & 7);       // l-independent source slot
    const unsigned char* aBase = A + (size_t)(rowBase + (tid >> 3)) * K + sg * 16;
    const unsigned char* bBase = Bw + (size_t)(colBase + (tid >> 3)) * K + sg * 16;
    unsigned char* ldsA = As + (tid & 192) * 16;
    unsigned char* ldsB = Bs + (tid & 192) * 16;

#pragma unroll 2
    for (int kt = 0; kt < K; kt += 128) {
#pragma unroll
        for (int l = 0; l < 4; ++l) {
            ASYNC_COPY16(aBase + (size_t)l * 32 * K + kt, ldsA + l * 4096);
            ASYNC_COPY16(bBase + (size_t)l * 32 * K + kt, ldsB + l * 4096);
        }
        WAITV0();
        __syncthreads();
#pragma unroll
        for (int kk = 0; kk < 4; ++kk) {
            // kk-th MFMA step covers logical 16B slots {2kk, 2kk+1};
            // lane's logical slot = 2kk + (q>>1), physical = logical ^ key
            const int sb = (((2 * kk + (q >> 1)) ^ key) << 4) + hb8;
            long af[4], bfr[4];
#pragma unroll
            for (int m = 0; m < 4; ++m) {
                const int row = wr * 64 + m * 16 + c;
                af[m] = *(const long*)((const char*)As + row * 128 + sb);
            }
#pragma unroll
            for (int n = 0; n < 4; ++n) {
                const int row = wc * 64 + n * 16 + c;
                bfr[n] = *(const long*)((const char*)Bs + row * 128 + sb);
            }
#pragma unroll
            for (int m = 0; m < 4; ++m)
#pragma unroll
                for (int n = 0; n < 4; ++n)
                    acc[m][n] = __builtin_amdgcn_mfma_f32_16x16x32_fp8_fp8(af[m], bfr[n], acc[m][n], 0, 0, 0);
        }
        __syncthreads();
    }

#pragma unroll
    for (int m = 0; m < 4; ++m) {
#pragma unroll
        for (int jj = 0; jj < 4; ++jj) {
            int grow = rowBase + wr * 64 + m * 16 + q * 4 + jj;
            float vv[4];
#pragma unroll
            for (int n = 0; n < 4; ++n)
                vv[n] = acc[m][n][jj] * invs + bias[colBase + wc * 64 + n * 16 + c];
            if constexpr (MODE == 0) {
                char* ob = (char*)outp;
                if (colBase < 1024) {
                    // Q/K: pi2 within-head pack; pair (n=0,1) -> ushort, pair (n=2,3) -> +32
                    int p0 = __builtin_amdgcn_cvt_pk_fp8_f32(vv[0] * 32.0f, vv[1] * 32.0f, 0, false);
                    int p1 = __builtin_amdgcn_cvt_pk_fp8_f32(vv[2] * 32.0f, vv[3] * 32.0f, 0, false);
                    *(unsigned short*)(ob + (size_t)grow * 2048 + colBase + wc * 64 + c * 2) =
                        (unsigned short)(p0 & 0xffff);
                    *(unsigned short*)(ob + (size_t)grow * 2048 + colBase + wc * 64 + 32 + c * 2) =
                        (unsigned short)(p1 & 0xffff);
                } else {
                    // V: bf16, pi2v within-head pack -> 2 dword stores
                    bf16 t0 = (bf16)vv[0], t1 = (bf16)vv[1], t2 = (bf16)vv[2], t3 = (bf16)vv[3];
                    unsigned int pk0 = ((unsigned int)*(unsigned short*)&t1 << 16) |
                                       (unsigned int)*(unsigned short*)&t0;
                    unsigned int pk1 = ((unsigned int)*(unsigned short*)&t3 << 16) |
                                       (unsigned int)*(unsigned short*)&t2;
                    size_t vb = (size_t)grow * 2048 + 1024 + (size_t)(colBase - 1024 + wc * 64) * 2;
                    *(unsigned int*)(ob + vb + c * 4) = pk0;
                    *(unsigned int*)(ob + vb + 64 + c * 4) = pk1;
                }
            } else if constexpr (MODE == 1) {
                // gelu each (fast rcp), pack 4 permuted-contiguous bytes, one dword store
#pragma unroll
                for (int n = 0; n < 4; ++n) {
                    float v = vv[n];
                    float e = __expf(1.5957691216057308f * (v + 0.044715f * v * v * v));
                    vv[n] = v * __fdividef(e, 1.0f + e) * 64.0f;
                }
                int p = __builtin_amdgcn_cvt_pk_fp8_f32(vv[0], vv[1], 0, false);
                p = __builtin_amdgcn_cvt_pk_fp8_f32(vv[2], vv[3], p, true);
                *(unsigned int*)((char*)outp + (size_t)grow * N + colBase + wc * 64 + c * 4) =
                    (unsigned int)p;
            } else {
#pragma unroll
                for (int n = 0; n < 4; ++n) {
                    int gcol = colBase + wc * 64 + n * 16 + c;
                    float v = vv[n];
                    if constexpr (MODE == 2) {
                        int g = grow >> 6, ns = grow & 63;
                        int b = g >> 6, i = (g >> 3) & 7, j = g & 7;
                        int a = ns >> 3, u = ns & 7;
                        int t = b * 4096 + (a * 8 + i) * 64 + (u * 8 + j);
                        size_t oi = (size_t)t * 512 + gcol;
                        ((float*)outp)[oi] = resid[oi] + v;
                    } else {
                        size_t oi = (size_t)grow * 512 + gcol;
                        ((float*)outp)[oi] = resid[oi] + v;
                    }
                }
            }
        }
    }
}

// ---------------- launcher ----------------
extern "C" void kernel_launch(void* const* d_in, const int* in_sizes, int n_in,
                              void* d_out, int out_size, void* d_ws, size_t ws_size,
                              hipStream_t stream)
{
    const float* x    = (const float*)d_in[0];
    const float* n1g  = (const float*)d_in[1];
    const float* n1b  = (const float*)d_in[2];
    const float* qkvw = (const float*)d_in[3];
    const float* qkvb = (const float*)d_in[4];
    const float* pjw  = (const float*)d_in[5];
    const float* pjb  = (const float*)d_in[6];
    const float* pw0  = (const float*)d_in[7];
    const float* pb0  = (const float*)d_in[8];
    const float* pg0  = (const float*)d_in[9];
    const float* pbb0 = (const float*)d_in[10];
    const float* pw1  = (const float*)d_in[11];
    const float* pb1  = (const float*)d_in[12];
    const float* pg1  = (const float*)d_in[13];
    const float* pbb1 = (const float*)d_in[14];
    const float* pw2  = (const float*)d_in[15];
    const float* pb2  = (const float*)d_in[16];
    const float* pg2  = (const float*)d_in[17];
    const float* pbb2 = (const float*)d_in[18];
    const float* pw3  = (const float*)d_in[19];
    const float* pb3  = (const float*)d_in[20];
    const float* n2g  = (const float*)d_in[21];
    const float* n2b  = (const float*)d_in[22];
    const float* w1   = (const float*)d_in[23];
    const float* b1   = (const float*)d_in[24];
    const float* w2   = (const float*)d_in[25];
    const float* b2   = (const float*)d_in[26];

    char* ws = (char*)d_ws;
    unsigned char* qkvw_f8 = (unsigned char*)(ws + OFF_QKVW);
    unsigned char* pjw_f8  = (unsigned char*)(ws + OFF_PROJW);
    unsigned char* w1_f8 = (unsigned char*)(ws + OFF_W1);
    unsigned char* w2_f8 = (unsigned char*)(ws + OFF_W2);
    float* ptab  = (float*)(ws + OFF_PTAB);
    unsigned char* bufA8 = (unsigned char*)(ws + OFF_A);   // qkv mixed / hidden fp8
    unsigned char* bufB8 = (unsigned char*)(ws + OFF_B);   // LN outs fp8 / attn-out fp8
    float* xout  = (float*)d_out;

    // weight casts (all fp8 x64; w2 K-permuted for MLP1's pi; pjw K-permuted for V's pi2v)
    cast_fp8_k<<<(1536 * 512 / 4 + 255) / 256, 256, 0, stream>>>(qkvw, qkvw_f8, 1536 * 512 / 4);
    cast_fp8_permv_k<<<(512 * 512 / 4 + 255) / 256, 256, 0, stream>>>(pjw, pjw_f8, 512 * 512 / 4, 512);
    cast_fp8_k<<<(2048 * 512 / 4 + 255) / 256, 256, 0, stream>>>(w1, w1_f8, 2048 * 512 / 4);
    cast_fp8_perm_k<<<(512 * 2048 / 4 + 255) / 256, 256, 0, stream>>>(w2, w2_f8, 512 * 2048 / 4, 2048);

    // pos-bias table
    posmlp_k<<<1, 256, 0, stream>>>(pw0, pb0, pg0, pbb0, pw1, pb1, pg1, pbb1,
                                    pw2, pb2, pg2, pbb2, pw3, pb3, ptab);

    // LN1 + group -> bufB (fp8 x32)
    ln_k<1><<<16384, 256, 0, stream>>>(x, n1g, n1b, bufB8);

    // QKV (fp8) -> bufA mixed layout [Qf8|Kf8|Vbf16] (Q/K pi2, V pi2v); invs = 1/(32*64)
    gemm_fp8<0, 12, 512><<<dim3(12, 512), 256, 0, stream>>>(bufB8, qkvw_f8, qkvb, nullptr,
                                                            bufA8, 1536, 1.0f / 2048.0f);

    // attention -> bufB (fp8 x32; O columns inherit V's pi2v order)
    attn_mfma_k<<<2048, 256, 0, stream>>>(bufA8, ptab, bufB8);

    // proj (fp8, pjw K-permuted) + ungroup + residual(x) -> d_out (x1); invs = 1/(32*64)
    gemm_fp8<2, 4, 512><<<dim3(4, 512), 256, 0, stream>>>(bufB8, pjw_f8, pjb, x,
                                                          xout, 512, 1.0f / 2048.0f);

    // LN2 -> bufB (fp8 x32)
    ln_k<0><<<16384, 256, 0, stream>>>(xout, n2g, n2b, bufB8);

    // MLP1 (fp8) + gelu -> bufA as fp8 x64, columns pi-permuted; invs = 1/(32*64)
    gemm_fp8<1, 16, 512><<<dim3(16, 512), 256, 0, stream>>>(bufB8, w1_f8, b1, nullptr,
                                                            bufA8, 2048, 1.0f / 2048.0f);

    // MLP2 (fp8, K-permuted both sides) + residual(x1) -> d_out; invs = 1/(64*64)
    gemm_fp8<3, 4, 2048><<<dim3(4, 512), 256, 0, stream>>>(bufA8, w2_f8, b2, xout,
                                                           xout, 512, 1.0f / 4096.0f);
}